// Round 8
// baseline (254.943 us; speedup 1.0000x reference)
//
#include <hip/hip_runtime.h>

// OnLSTMCell fused pipeline for MI355X (gfx950).
// B=8192, input=1024, hidden=1024, level=64, d_in=2048.
// ws layout (bytes), total ~117 MB:
//   A_HI   @ 0          : u16[8192*2048]  (32 MB)   bf16(concat(input,h_prev))
//   A_LO   @ 33554432   : u16[8192*2048]  (32 MB)   bf16 residual (level path precision)
//   W_HI   @ 67108864   : u16[4224*2048]  (16.5 MB) rows 0..4095 gate-interleaved (n=j*4+gate), 4096..4223 = W_level
//   WLEV_LO@ 84410368   : u16[128*2048]   (0.5 MB)
//   PART   @ 84934656   : f32[8][8192][128] (32 MB) split-K partials of level GEMM
//   IH     @ 118489088  : f32[8192*64]    (2 MB)
//   FH     @ 120586240  : f32[8192*64]    (2 MB)

typedef unsigned short u16;
typedef __attribute__((ext_vector_type(8))) short bf16x8;
typedef __attribute__((ext_vector_type(8))) short s8v;
typedef __attribute__((ext_vector_type(4))) float f32x4;
typedef __attribute__((ext_vector_type(4))) float v4f;

#define GLDS(g, l) __builtin_amdgcn_global_load_lds(                      \
    (const __attribute__((address_space(1))) void*)(g),                   \
    (__attribute__((address_space(3))) void*)(l), 16, 0, 0)

__device__ __forceinline__ u16 f2bf(float x) {
  unsigned u = __builtin_bit_cast(unsigned, x);
  u += 0x7FFFu + ((u >> 16) & 1u);
  return (u16)(u >> 16);
}
__device__ __forceinline__ float bf2f(u16 h) {
  unsigned u = ((unsigned)h) << 16;
  return __builtin_bit_cast(float, u);
}
__device__ __forceinline__ float fsig(float x) { return 1.0f / (1.0f + __expf(-x)); }
__device__ __forceinline__ float ftanhf(float x) { float e = __expf(2.0f * x); return 1.0f - 2.0f / (e + 1.0f); }

// ---------------------------------------------------------------- convert ---
__global__ __launch_bounds__(256) void k_convert(
    const float* __restrict__ inp, const float* __restrict__ hprev,
    const float* __restrict__ wl, const float* __restrict__ wlev,
    u16* __restrict__ Ahi, u16* __restrict__ Alo,
    u16* __restrict__ Whi, u16* __restrict__ Wlo)
{
  const int GA = (8192 * 2048) / 8;
  const int GW = (4224 * 2048) / 8;
  for (int gi = blockIdx.x * 256 + threadIdx.x; gi < GA + GW; gi += gridDim.x * 256) {
    if (gi < GA) {
      int e = gi << 3; int row = e >> 11, col = e & 2047;
      const float* src = (col < 1024) ? (inp + row * 1024 + col)
                                      : (hprev + row * 1024 + (col - 1024));
      v4f a = *(const v4f*)src, b = *(const v4f*)(src + 4);
      float vv[8] = {a.x, a.y, a.z, a.w, b.x, b.y, b.z, b.w};
      s8v hi, lo;
#pragma unroll
      for (int j = 0; j < 8; ++j) {
        u16 h = f2bf(vv[j]);
        hi[j] = (short)h;
        lo[j] = (short)f2bf(vv[j] - bf2f(h));
      }
      *(s8v*)(Ahi + e) = hi;
      *(s8v*)(Alo + e) = lo;
    } else {
      int e = (gi - GA) << 3; int n = e >> 11, k = e & 2047;
      const float* src;
      if (n < 4096) { int j = n >> 2, g = n & 3; src = wl + (size_t)((g << 10) | j) * 2048 + k; }
      else          { src = wlev + (size_t)(n - 4096) * 2048 + k; }
      v4f a = *(const v4f*)src, b = *(const v4f*)(src + 4);
      float vv[8] = {a.x, a.y, a.z, a.w, b.x, b.y, b.z, b.w};
      s8v hi, lo;
#pragma unroll
      for (int j = 0; j < 8; ++j) {
        u16 h = f2bf(vv[j]);
        hi[j] = (short)h;
        lo[j] = (short)f2bf(vv[j] - bf2f(h));
      }
      *(s8v*)(Whi + e) = hi;
      if (n >= 4096) *(s8v*)(Wlo + (size_t)(n - 4096) * 2048 + k) = lo;
    }
  }
}

// ----------------------------------------------- level GEMM (split-bf16) ---
__global__ __launch_bounds__(256) void k_gemm_level(
    const u16* __restrict__ Ahi, const u16* __restrict__ Alo,
    const u16* __restrict__ Whi, const u16* __restrict__ Wlo,
    float* __restrict__ part)
{
  __shared__ __align__(16) u16 smem[4 * 8192];
  u16 *Ah = smem, *Al = smem + 8192, *Bh = smem + 16384, *Bl = smem + 24576;
  const int tid = threadIdx.x, lane = tid & 63, wid = tid >> 6;
  const int wm = wid >> 1, wn = wid & 1;
  const int rm = blockIdx.x, s = blockIdx.y;
  const int lrow = lane >> 3, lcolE = (lane & 7) << 3;
  const int c16 = lane & 15, r16 = lane >> 4;
  f32x4 acc[4][4] = {};
  const u16* aBaseH = Ahi + (size_t)(rm << 7) * 2048;
  const u16* aBaseL = Alo + (size_t)(rm << 7) * 2048;
  const u16* bBaseH = Whi + (size_t)4096 * 2048;

  for (int kt = 0; kt < 4; ++kt) {
    const int k0 = (s << 8) + (kt << 6);
#pragma unroll
    for (int q = 0; q < 4; ++q) {
      const int ca = (wid << 2) + q;
      size_t roff = (size_t)((ca << 3) + lrow) * 2048 + k0 + lcolE;
      GLDS(aBaseH + roff, Ah + (ca << 9));
      GLDS(aBaseL + roff, Al + (ca << 9));
      GLDS(bBaseH + roff, Bh + (ca << 9));
      GLDS(Wlo + roff,    Bl + (ca << 9));
    }
    __syncthreads();
#pragma unroll
    for (int ks = 0; ks < 2; ++ks) {
      bf16x8 ah[4], al[4];
#pragma unroll
      for (int i = 0; i < 4; ++i) {
        int off = ((wm << 6) + (i << 4) + c16) * 64 + (ks << 5) + (r16 << 3);
        ah[i] = *(const bf16x8*)(Ah + off);
        al[i] = *(const bf16x8*)(Al + off);
      }
#pragma unroll
      for (int j = 0; j < 4; ++j) {
        int off = ((wn << 6) + (j << 4) + c16) * 64 + (ks << 5) + (r16 << 3);
        bf16x8 bh = *(const bf16x8*)(Bh + off);
        bf16x8 bl = *(const bf16x8*)(Bl + off);
#pragma unroll
        for (int i = 0; i < 4; ++i) {
          acc[i][j] = __builtin_amdgcn_mfma_f32_16x16x32_bf16(ah[i], bh, acc[i][j], 0, 0, 0);
          acc[i][j] = __builtin_amdgcn_mfma_f32_16x16x32_bf16(al[i], bh, acc[i][j], 0, 0, 0);
          acc[i][j] = __builtin_amdgcn_mfma_f32_16x16x32_bf16(ah[i], bl, acc[i][j], 0, 0, 0);
        }
      }
    }
    __syncthreads();
  }
#pragma unroll
  for (int mi = 0; mi < 4; ++mi)
#pragma unroll
    for (int ni = 0; ni < 4; ++ni)
#pragma unroll
      for (int r = 0; r < 4; ++r) {
        int ml = (wm << 6) + (mi << 4) + (r16 << 2) + r;
        int nl = (wn << 6) + (ni << 4) + c16;
        part[(size_t)((s << 13) + (rm << 7) + ml) * 128 + nl] = acc[mi][ni][r];
      }
}

// ------------------------------------------- softmax + cumsums (per row) ---
__global__ __launch_bounds__(256) void k_softmax(
    const float* __restrict__ part, float* __restrict__ ih, float* __restrict__ fh)
{
  const int tid = threadIdx.x, lane = tid & 63, w = tid >> 6;
  const int row = blockIdx.x * 4 + w;
  float vi = 0.f, vf = 0.f;
#pragma unroll
  for (int s = 0; s < 8; ++s) {
    vi += part[(size_t)((s << 13) + row) * 128 + lane];
    vf += part[(size_t)((s << 13) + row) * 128 + 64 + lane];
  }
  float mi = vi, mf = vf;
#pragma unroll
  for (int d = 1; d < 64; d <<= 1) {
    mi = fmaxf(mi, __shfl_xor(mi, d, 64));
    mf = fmaxf(mf, __shfl_xor(mf, d, 64));
  }
  float ei = __expf(vi - mi), ef = __expf(vf - mf);
  float si = ei, sf = ef;
#pragma unroll
  for (int d = 1; d < 64; d <<= 1) {
    si += __shfl_xor(si, d, 64);
    sf += __shfl_xor(sf, d, 64);
  }
  float pi = ei / si, pf = ef / sf;
  float ci = pi, cf = pf;
#pragma unroll
  for (int d = 1; d < 64; d <<= 1) {
    float t = __shfl_up(ci, d, 64); if (lane >= d) ci += t;
    float u = __shfl_up(cf, d, 64); if (lane >= d) cf += u;
  }
  ih[(row << 6) + lane] = 1.0f - (ci - pi);
  fh[(row << 6) + lane] = cf;
}

// -------------------------------------- main gates GEMM + fused epilogue ---
// m201-style 8-phase port. 256x256 tile, 512 thr = 8 waves (2M x 4N),
// wave-tile 128x64, acc[8][4] f32x4 (AGPRs). BK=64, 32 K-tiles.
// LDS = 2 x 64 KB double buffer (buf = tile%2); each K-tile buffer holds
// 8 chunks [op(A/B)][kh][rh] of [128 rows][32 k] = 8 KB (rows 64 B, 16-B
// k-slots swizzled slot^=(row>>1)&3 -> 2-way bank access, free per m136).
// Per K-tile, 4 phases (quadrant ih,jh per wave; 16 MFMA each):
//  P1: 12 ds_read (A ih0 8 + B jh0 4); bar; lgkm0; prio; MM(0,0); bar.
//  P2:  4 ds_read (B jh1);             bar; lgkm0; prio; MM(0,1); bar.
//  P3:  8 ds_read (A ih1);             bar; lgkm0; prio; MM(1,0); bar.
//  P4: STAGE8(t+2 -> same buf); vmcnt(8); bar; prio; MM(1,1); bar.
// RAW: vmcnt(8) at tile t retires stage(t+1) (outstanding = t+1's 8 +
// t+2's 8) before the barriers preceding tile t+1's reads. WAR: stage(t+2)
// overwrites the buffer tile t reads, but A's last ds_read is P3 and B's
// is P2, both published by their phase's lgkmcnt(0)+barrier before P4's
// stage issues. Never vmcnt(0) until peeled tile 30. Tiles 30,31 peeled
// (no stage, no wrap dummies).
__global__ __launch_bounds__(512, 2) void k_gemm_main(
    const u16* __restrict__ Ab, const u16* __restrict__ Wb,
    const float* __restrict__ cprev, const float* __restrict__ ihp,
    const float* __restrict__ fhp, float* __restrict__ out)
{
  __shared__ __align__(16) u16 smem[65536];        // 128 KB; epi reuses 64 KB
  const int tid = threadIdx.x, lane = tid & 63, wid = tid >> 6;
  const int wm = wid >> 2, wn = wid & 3;           // 2 x 4 wave grid
  const int c16 = lane & 15, r16 = lane >> 4;

  // r3-proven XCD swizzle: 512 blocks = 8 XCD x 64; rm slow / cm fast
  // within XCD -> A panels L2-resident, W re-reads absorbed by L3.
  const int bx = blockIdx.x;
  const int nb = (bx & 7) * 64 + (bx >> 3);
  const int rm = nb >> 4, cm = nb & 15;            // 32 row x 16 col tiles

  // staging map: thread -> row sr (0..127), 16B slot slq; global src
  // pre-permuted (slq ^ (sr>>1)&3) so the linear GLDS dest is swizzled.
  const int sr = tid >> 2;
  const int slq = tid & 3;
  const int sx = (slq ^ ((sr >> 1) & 3)) << 3;     // elements
  const u16* pa = Ab + (size_t)(rm * 256 + sr) * 2048 + sx;
  const u16* pb = Wb + (size_t)(cm * 256 + sr) * 2048 + sx;
  char* const ldsT = (char*)smem + (wid << 10);    // + lane*16 by GLDS

  // ds_read: swizzle slot term is lane-invariant across frags (all frag row
  // offsets are multiples of 16): xsl = (r16 ^ ((c16>>1)&3))*16 bytes.
  const char* const lbase = (const char*)smem;
  const int xsl = (r16 ^ ((c16 >> 1) & 3)) << 4;
  const int aBase = wm * 8192 + c16 * 64 + xsl;                    // +buf*65536 +kh*16384 +ih*4096 +fi*1024
  const int bBase = 32768 + (wn >> 1) * 8192 + ((wn & 1) * 64 + c16) * 64 + xsl; // +kh*16384 +jh*2048 +fj*1024

  f32x4 acc[8][4] = {};
  bf16x8 aX[4][2];        // A frags of current ih: [fi][kh]
  bf16x8 bS[2][2][2];     // B frags: [jh][fj][kh], live across the K-tile

#define RD_A(buf_, ih_)                                                \
    _Pragma("unroll")                                                  \
    for (int fi = 0; fi < 4; ++fi)                                     \
      _Pragma("unroll")                                                \
      for (int kh = 0; kh < 2; ++kh)                                   \
        aX[fi][kh] = *(const bf16x8*)(lbase + (buf_) * 65536 +         \
            kh * 16384 + aBase + (ih_) * 4096 + fi * 1024);

#define RD_B(buf_, jh_)                                                \
    _Pragma("unroll")                                                  \
    for (int fj = 0; fj < 2; ++fj)                                     \
      _Pragma("unroll")                                                \
      for (int kh = 0; kh < 2; ++kh)                                   \
        bS[jh_][fj][kh] = *(const bf16x8*)(lbase + (buf_) * 65536 +    \
            kh * 16384 + bBase + (jh_) * 2048 + fj * 1024);

#define MM(ih_, jh_)                                                   \
    _Pragma("unroll")                                                  \
    for (int fi = 0; fi < 4; ++fi)                                     \
      _Pragma("unroll")                                                \
      for (int fj = 0; fj < 2; ++fj)                                   \
        _Pragma("unroll")                                              \
        for (int kh = 0; kh < 2; ++kh)                                 \
          acc[(ih_) * 4 + fi][(jh_) * 2 + fj] =                        \
              __builtin_amdgcn_mfma_f32_16x16x32_bf16(aX[fi][kh],      \
                  bS[jh_][fj][kh], acc[(ih_) * 4 + fi][(jh_) * 2 + fj], 0, 0, 0);

#define STAGE8(t2_, buf_) do {                                         \
    _Pragma("unroll")                                                  \
    for (int c = 0; c < 8; ++c) {                                      \
      const int op_ = c >> 2, kh_ = (c >> 1) & 1, rh_ = c & 1;         \
      GLDS((op_ ? pb : pa) + rh_ * 262144 + (t2_) * 64 + kh_ * 32,     \
           ldsT + (buf_) * 65536 + op_ * 32768 + kh_ * 16384 + rh_ * 8192); \
    }                                                                  \
  } while (0)

#define BAR() __builtin_amdgcn_s_barrier()
#define LGKM0() asm volatile("s_waitcnt lgkmcnt(0)" ::: "memory")
#define PRIO(v) __builtin_amdgcn_s_setprio(v)

#define TILE(buf_, t2_, dostage_, lastvm_) do {                        \
    RD_A(buf_, 0); RD_B(buf_, 0);                                      \
    BAR(); LGKM0(); PRIO(1); MM(0, 0); PRIO(0); BAR();                 \
    RD_B(buf_, 1);                                                     \
    BAR(); LGKM0(); PRIO(1); MM(0, 1); PRIO(0); BAR();                 \
    RD_A(buf_, 1);                                                     \
    BAR(); LGKM0(); PRIO(1); MM(1, 0); PRIO(0); BAR();                 \
    if (dostage_) {                                                    \
      STAGE8((t2_), (buf_));                                           \
      asm volatile("s_waitcnt vmcnt(8)" ::: "memory");                 \
    }                                                                  \
    if (lastvm_) asm volatile("s_waitcnt vmcnt(0)" ::: "memory");      \
    BAR(); PRIO(1); MM(1, 1); PRIO(0); BAR();                          \
  } while (0)

  // prologue: tiles 0,1 -> bufs 0,1 (16 GLDS); vmcnt(8) forces tile 0.
  STAGE8(0, 0);
  STAGE8(1, 1);
  asm volatile("s_waitcnt vmcnt(8)" ::: "memory");
  BAR();

  for (int u = 0; u < 15; ++u) {                   // tiles 0..29
    TILE(0, 2 * u + 2, 1, 0);
    TILE(1, 2 * u + 3, 1, 0);
  }
  TILE(0, 0, 0, 1);                                // tile 30: drain stage(31)
  TILE(1, 0, 0, 0);                                // tile 31
#undef TILE
#undef STAGE8
#undef MM
#undef RD_B
#undef RD_A

  BAR();                                           // LDS reuse boundary

  // ---- fused ON-LSTM epilogue: 4 row-passes, epi = f32[64][256] (64 KB) ----
  // LITERAL pass index (rule #20): all acc[] subscripts compile-time.
  float* epi = (float*)smem;
#define EPIPASS(p) do {                                                \
    if (wm == ((p) >> 1)) {                                            \
      _Pragma("unroll")                                                \
      for (int iq = 0; iq < 4; ++iq)                                   \
        _Pragma("unroll")                                              \
        for (int j = 0; j < 4; ++j)                                    \
          _Pragma("unroll")                                            \
          for (int r = 0; r < 4; ++r) {                                \
            float v = acc[((p) & 1) * 4 + iq][j][r];                   \
            v = ((c16 & 3) == 3) ? ftanhf(v) : fsig(v);                \
            epi[(iq * 16 + r16 * 4 + r) * 256 + wn * 64 + j * 16 + c16] = v; \
          }                                                            \
    }                                                                  \
    __syncthreads();                                                   \
    _Pragma("unroll")                                                  \
    for (int e = 0; e < 8; ++e) {                                      \
      int idx = (e << 9) + tid;                                        \
      int m = idx >> 6, jl = idx & 63;                                 \
      v4f v = *(const v4f*)(epi + m * 256 + (jl << 2));                \
      int rowg = rm * 256 + (p) * 64 + m;                              \
      int jg = cm * 64 + jl;                                           \
      float cp = cprev[rowg * 1024 + jg];                              \
      int lv = jg >> 4;                                                \
      float vih = ihp[(rowg << 6) + lv], vfh = fhp[(rowg << 6) + lv];  \
      float iv = v.x, fv = v.y, ov = v.z, gv = v.w;                    \
      float wq = vih * vfh;                                            \
      float c = wq * (fv * cp + iv * gv) + (vfh - wq) * cp + (vih - wq) * gv; \
      float h = ov * ftanhf(c);                                        \
      out[rowg * 1024 + jg] = h;                                       \
      out[8388608 + rowg * 1024 + jg] = c;                             \
    }                                                                  \
    __syncthreads();                                                   \
  } while (0)
  EPIPASS(0); EPIPASS(1); EPIPASS(2); EPIPASS(3);
#undef EPIPASS
}

// -------------------------------------------------------------- launcher ---
extern "C" void kernel_launch(void* const* d_in, const int* in_sizes, int n_in,
                              void* d_out, int out_size, void* d_ws, size_t ws_size,
                              hipStream_t stream) {
  (void)in_sizes; (void)n_in; (void)out_size; (void)ws_size;
  const float* inp   = (const float*)d_in[0];
  const float* hprev = (const float*)d_in[1];
  const float* cprev = (const float*)d_in[2];
  const float* wl    = (const float*)d_in[3];
  const float* wlev  = (const float*)d_in[4];
  float* out = (float*)d_out;
  char* ws = (char*)d_ws;

  u16* Ahi  = (u16*)(ws);
  u16* Alo  = (u16*)(ws + 33554432);
  u16* Whi  = (u16*)(ws + 67108864);
  u16* Wlo  = (u16*)(ws + 84410368);
  float* part = (float*)(ws + 84934656);
  float* ih   = (float*)(ws + 118489088);
  float* fh   = (float*)(ws + 120586240);

  k_convert<<<dim3(2048), dim3(256), 0, stream>>>(inp, hprev, wl, wlev, Ahi, Alo, Whi, Wlo);
  k_gemm_level<<<dim3(64, 8), dim3(256), 0, stream>>>(Ahi, Alo, Whi, Wlo, part);
  k_softmax<<<dim3(2048), dim3(256), 0, stream>>>(part, ih, fh);
  k_gemm_main<<<dim3(512), dim3(512), 0, stream>>>(Ahi, Whi, cprev, ih, fh, out);
}

// Round 9
// 242.017 us; speedup vs baseline: 1.0534x; 1.0534x over previous
//
#include <hip/hip_runtime.h>

// OnLSTMCell fused pipeline for MI355X (gfx950).
// B=8192, input=1024, hidden=1024, level=64, d_in=2048.
// ws layout (bytes), total ~117 MB:
//   A_HI   @ 0          : u16[8192*2048]  (32 MB)   bf16(concat(input,h_prev))
//   A_LO   @ 33554432   : u16[8192*2048]  (32 MB)   bf16 residual (level path precision)
//   W_HI   @ 67108864   : u16[4224*2048]  (16.5 MB) rows 0..4095 gate-interleaved (n=j*4+gate), 4096..4223 = W_level
//   WLEV_LO@ 84410368   : u16[128*2048]   (0.5 MB)
//   PART   @ 84934656   : f32[8][8192][128] (32 MB) split-K partials of level GEMM
//   IH     @ 118489088  : f32[8192*64]    (2 MB)
//   FH     @ 120586240  : f32[8192*64]    (2 MB)

typedef unsigned short u16;
typedef __attribute__((ext_vector_type(8))) short bf16x8;
typedef __attribute__((ext_vector_type(8))) short s8v;
typedef __attribute__((ext_vector_type(4))) float f32x4;
typedef __attribute__((ext_vector_type(4))) float v4f;

#define GLDS(g, l) __builtin_amdgcn_global_load_lds(                      \
    (const __attribute__((address_space(1))) void*)(g),                   \
    (__attribute__((address_space(3))) void*)(l), 16, 0, 0)

__device__ __forceinline__ u16 f2bf(float x) {
  unsigned u = __builtin_bit_cast(unsigned, x);
  u += 0x7FFFu + ((u >> 16) & 1u);
  return (u16)(u >> 16);
}
__device__ __forceinline__ float bf2f(u16 h) {
  unsigned u = ((unsigned)h) << 16;
  return __builtin_bit_cast(float, u);
}
__device__ __forceinline__ float fsig(float x) { return 1.0f / (1.0f + __expf(-x)); }
__device__ __forceinline__ float ftanhf(float x) { float e = __expf(2.0f * x); return 1.0f - 2.0f / (e + 1.0f); }

// ---------------------------------------------------------------- convert ---
__global__ __launch_bounds__(256) void k_convert(
    const float* __restrict__ inp, const float* __restrict__ hprev,
    const float* __restrict__ wl, const float* __restrict__ wlev,
    u16* __restrict__ Ahi, u16* __restrict__ Alo,
    u16* __restrict__ Whi, u16* __restrict__ Wlo)
{
  const int GA = (8192 * 2048) / 8;
  const int GW = (4224 * 2048) / 8;
  for (int gi = blockIdx.x * 256 + threadIdx.x; gi < GA + GW; gi += gridDim.x * 256) {
    if (gi < GA) {
      int e = gi << 3; int row = e >> 11, col = e & 2047;
      const float* src = (col < 1024) ? (inp + row * 1024 + col)
                                      : (hprev + row * 1024 + (col - 1024));
      v4f a = *(const v4f*)src, b = *(const v4f*)(src + 4);
      float vv[8] = {a.x, a.y, a.z, a.w, b.x, b.y, b.z, b.w};
      s8v hi, lo;
#pragma unroll
      for (int j = 0; j < 8; ++j) {
        u16 h = f2bf(vv[j]);
        hi[j] = (short)h;
        lo[j] = (short)f2bf(vv[j] - bf2f(h));
      }
      *(s8v*)(Ahi + e) = hi;
      *(s8v*)(Alo + e) = lo;
    } else {
      int e = (gi - GA) << 3; int n = e >> 11, k = e & 2047;
      const float* src;
      if (n < 4096) { int j = n >> 2, g = n & 3; src = wl + (size_t)((g << 10) | j) * 2048 + k; }
      else          { src = wlev + (size_t)(n - 4096) * 2048 + k; }
      v4f a = *(const v4f*)src, b = *(const v4f*)(src + 4);
      float vv[8] = {a.x, a.y, a.z, a.w, b.x, b.y, b.z, b.w};
      s8v hi, lo;
#pragma unroll
      for (int j = 0; j < 8; ++j) {
        u16 h = f2bf(vv[j]);
        hi[j] = (short)h;
        lo[j] = (short)f2bf(vv[j] - bf2f(h));
      }
      *(s8v*)(Whi + e) = hi;
      if (n >= 4096) *(s8v*)(Wlo + (size_t)(n - 4096) * 2048 + k) = lo;
    }
  }
}

// ----------------------------------------------- level GEMM (split-bf16) ---
__global__ __launch_bounds__(256) void k_gemm_level(
    const u16* __restrict__ Ahi, const u16* __restrict__ Alo,
    const u16* __restrict__ Whi, const u16* __restrict__ Wlo,
    float* __restrict__ part)
{
  __shared__ __align__(16) u16 smem[4 * 8192];
  u16 *Ah = smem, *Al = smem + 8192, *Bh = smem + 16384, *Bl = smem + 24576;
  const int tid = threadIdx.x, lane = tid & 63, wid = tid >> 6;
  const int wm = wid >> 1, wn = wid & 1;
  const int rm = blockIdx.x, s = blockIdx.y;
  const int lrow = lane >> 3, lcolE = (lane & 7) << 3;
  const int c16 = lane & 15, r16 = lane >> 4;
  f32x4 acc[4][4] = {};
  const u16* aBaseH = Ahi + (size_t)(rm << 7) * 2048;
  const u16* aBaseL = Alo + (size_t)(rm << 7) * 2048;
  const u16* bBaseH = Whi + (size_t)4096 * 2048;

  for (int kt = 0; kt < 4; ++kt) {
    const int k0 = (s << 8) + (kt << 6);
#pragma unroll
    for (int q = 0; q < 4; ++q) {
      const int ca = (wid << 2) + q;
      size_t roff = (size_t)((ca << 3) + lrow) * 2048 + k0 + lcolE;
      GLDS(aBaseH + roff, Ah + (ca << 9));
      GLDS(aBaseL + roff, Al + (ca << 9));
      GLDS(bBaseH + roff, Bh + (ca << 9));
      GLDS(Wlo + roff,    Bl + (ca << 9));
    }
    __syncthreads();
#pragma unroll
    for (int ks = 0; ks < 2; ++ks) {
      bf16x8 ah[4], al[4];
#pragma unroll
      for (int i = 0; i < 4; ++i) {
        int off = ((wm << 6) + (i << 4) + c16) * 64 + (ks << 5) + (r16 << 3);
        ah[i] = *(const bf16x8*)(Ah + off);
        al[i] = *(const bf16x8*)(Al + off);
      }
#pragma unroll
      for (int j = 0; j < 4; ++j) {
        int off = ((wn << 6) + (j << 4) + c16) * 64 + (ks << 5) + (r16 << 3);
        bf16x8 bh = *(const bf16x8*)(Bh + off);
        bf16x8 bl = *(const bf16x8*)(Bl + off);
#pragma unroll
        for (int i = 0; i < 4; ++i) {
          acc[i][j] = __builtin_amdgcn_mfma_f32_16x16x32_bf16(ah[i], bh, acc[i][j], 0, 0, 0);
          acc[i][j] = __builtin_amdgcn_mfma_f32_16x16x32_bf16(al[i], bh, acc[i][j], 0, 0, 0);
          acc[i][j] = __builtin_amdgcn_mfma_f32_16x16x32_bf16(ah[i], bl, acc[i][j], 0, 0, 0);
        }
      }
    }
    __syncthreads();
  }
#pragma unroll
  for (int mi = 0; mi < 4; ++mi)
#pragma unroll
    for (int ni = 0; ni < 4; ++ni)
#pragma unroll
      for (int r = 0; r < 4; ++r) {
        int ml = (wm << 6) + (mi << 4) + (r16 << 2) + r;
        int nl = (wn << 6) + (ni << 4) + c16;
        part[(size_t)((s << 13) + (rm << 7) + ml) * 128 + nl] = acc[mi][ni][r];
      }
}

// ------------------------------------------- softmax + cumsums (per row) ---
__global__ __launch_bounds__(256) void k_softmax(
    const float* __restrict__ part, float* __restrict__ ih, float* __restrict__ fh)
{
  const int tid = threadIdx.x, lane = tid & 63, w = tid >> 6;
  const int row = blockIdx.x * 4 + w;
  float vi = 0.f, vf = 0.f;
#pragma unroll
  for (int s = 0; s < 8; ++s) {
    vi += part[(size_t)((s << 13) + row) * 128 + lane];
    vf += part[(size_t)((s << 13) + row) * 128 + 64 + lane];
  }
  float mi = vi, mf = vf;
#pragma unroll
  for (int d = 1; d < 64; d <<= 1) {
    mi = fmaxf(mi, __shfl_xor(mi, d, 64));
    mf = fmaxf(mf, __shfl_xor(mf, d, 64));
  }
  float ei = __expf(vi - mi), ef = __expf(vf - mf);
  float si = ei, sf = ef;
#pragma unroll
  for (int d = 1; d < 64; d <<= 1) {
    si += __shfl_xor(si, d, 64);
    sf += __shfl_xor(sf, d, 64);
  }
  float pi = ei / si, pf = ef / sf;
  float ci = pi, cf = pf;
#pragma unroll
  for (int d = 1; d < 64; d <<= 1) {
    float t = __shfl_up(ci, d, 64); if (lane >= d) ci += t;
    float u = __shfl_up(cf, d, 64); if (lane >= d) cf += u;
  }
  ih[(row << 6) + lane] = 1.0f - (ci - pi);
  fh[(row << 6) + lane] = cf;
}

// -------------------------------------- main gates GEMM + fused epilogue ---
// 256x256 tile, 512 thr = 8 waves (2M x 4N), wave-tile 128x64, acc[8][4]
// f32x4 (AGPRs). BK=64, 32 K-tiles, 2 x 64KB LDS dbuf (chunks [op][kh][rh]
// of [128 rows][64 B], 16-B slots swizzled slot^=(row>>1)&3, both sides).
// COUNTED-LGKM PREFETCH SCHEDULE (the r8 fix): 4 phases/tile, 16 MFMA each.
//  P0(kh0): issue {A fi0-3 self, B fj0-3 self, A fi4-7 prefetch(newest)} +
//           stage A-kh0(t+1); BAR; lgkmcnt(4) [drains self, prefetch flies
//           under MFMA]; 16 MFMA (fi0-3); BAR.
//  P1(kh0): stage B-kh0(t+1); BAR; lgkmcnt(0) [free]; 16 MFMA (fi4-7,
//           prefetched); vmcnt(4); BAR.
//  P2(kh1), P3(kh1): same pattern; P3 tail vmcnt(4).
// vmcnt ledger (2 GLDS per phase, 8/tile): @P1: outstanding = t-1{P2,P3}(4)
// + t{P0,P1}(4) -> retires t-1's = this tile's kh1 chunks (deadline P2).
// @P3: outstanding = t{P0..P3}(8) -> retires t{P0,P1} = kh0 of t+1
// (deadline t+1 P0). Never vmcnt(0) until tile 31. WAR: stage(t+1) chunk X
// overwrites buf^1's X, last read >=3 barriers earlier. Tiles 30,31 peeled.
__global__ __launch_bounds__(512, 2) void k_gemm_main(
    const u16* __restrict__ Ab, const u16* __restrict__ Wb,
    const float* __restrict__ cprev, const float* __restrict__ ihp,
    const float* __restrict__ fhp, float* __restrict__ out)
{
  __shared__ __align__(16) u16 smem[65536];        // 128 KB; epi reuses 64 KB
  const int tid = threadIdx.x, lane = tid & 63, wid = tid >> 6;
  const int wm = wid >> 2, wn = wid & 3;           // 2 x 4 wave grid
  const int c16 = lane & 15, r16 = lane >> 4;

  // r3-proven XCD swizzle: 512 blocks = 8 XCD x 64; rm slow / cm fast.
  const int bx = blockIdx.x;
  const int nb = (bx & 7) * 64 + (bx >> 3);
  const int rm = nb >> 4, cm = nb & 15;            // 32 row x 16 col tiles

  // staging map (validated r8): row sr=tid>>2, slot slq=tid&3, src
  // pre-permuted (slq ^ (sr>>1)&3) so linear GLDS dest is swizzled.
  const int sr = tid >> 2;
  const int slq = tid & 3;
  const int sx = (slq ^ ((sr >> 1) & 3)) << 3;
  const u16* pa = Ab + (size_t)(rm * 256 + sr) * 2048 + sx;
  const u16* pb = Wb + (size_t)(cm * 256 + sr) * 2048 + sx;
  char* const ldsT = (char*)smem + (wid << 10);

  // ds_read bases (validated r8): xsl lane-invariant swizzle term.
  const char* const lbase = (const char*)smem;
  const int xsl = (r16 ^ ((c16 >> 1) & 3)) << 4;
  const int aBase = wm * 8192 + c16 * 64 + xsl;                          // +buf*65536 +kh*16384 +fi8*1024
  const int bBase = 32768 + (wn >> 1) * 8192 + ((wn & 1) * 64 + c16) * 64 + xsl; // +fj4*1024

  f32x4 acc[8][4] = {};
  bf16x8 aP0, aP1, aP2, aP3, aQ0, aQ1, aQ2, aQ3, bq0, bq1, bq2, bq3;

#define RA(dst, bufR_, kh_, fi8_) dst = *(const bf16x8*)(lbase +        \
    (bufR_) * 65536 + (kh_) * 16384 + aBase + (fi8_) * 1024)
#define RB(dst, bufR_, kh_, fj4_) dst = *(const bf16x8*)(lbase +        \
    (bufR_) * 65536 + (kh_) * 16384 + bBase + (fj4_) * 1024)
#define STG2(t2_, bufW_, op_, kh_) do {                                 \
    GLDS(((op_) ? pb : pa) + (t2_) * 64 + (kh_) * 32,                   \
         ldsT + (bufW_) * 65536 + (op_) * 32768 + (kh_) * 16384);       \
    GLDS(((op_) ? pb : pa) + 262144 + (t2_) * 64 + (kh_) * 32,          \
         ldsT + (bufW_) * 65536 + (op_) * 32768 + (kh_) * 16384 + 8192);\
  } while (0)
#define MMROW(fi_, Af)                                                  \
    acc[fi_][0] = __builtin_amdgcn_mfma_f32_16x16x32_bf16(Af, bq0, acc[fi_][0], 0, 0, 0); \
    acc[fi_][1] = __builtin_amdgcn_mfma_f32_16x16x32_bf16(Af, bq1, acc[fi_][1], 0, 0, 0); \
    acc[fi_][2] = __builtin_amdgcn_mfma_f32_16x16x32_bf16(Af, bq2, acc[fi_][2], 0, 0, 0); \
    acc[fi_][3] = __builtin_amdgcn_mfma_f32_16x16x32_bf16(Af, bq3, acc[fi_][3], 0, 0, 0);
#define BAR() __builtin_amdgcn_s_barrier()
#define LGKM(n) asm volatile("s_waitcnt lgkmcnt(" #n ")" ::: "memory")
#define VMC(n) asm volatile("s_waitcnt vmcnt(" #n ")" ::: "memory")
#define PRIO(v) __builtin_amdgcn_s_setprio(v)

// one K-half (kh_): P-even {self A quad + B + prefetch A quad (newest) +
// stage opA}, P-odd {stage opB, MFMA prefetched quad, vmcnt tail}.
#define HALF(bufR_, kh_, t2_, bufW_, DOSTG, VMTAIL1) do {               \
    RA(aP0, bufR_, kh_, 0); RA(aP1, bufR_, kh_, 1);                     \
    RA(aP2, bufR_, kh_, 2); RA(aP3, bufR_, kh_, 3);                     \
    RB(bq0, bufR_, kh_, 0); RB(bq1, bufR_, kh_, 1);                     \
    RB(bq2, bufR_, kh_, 2); RB(bq3, bufR_, kh_, 3);                     \
    RA(aQ0, bufR_, kh_, 4); RA(aQ1, bufR_, kh_, 5);                     \
    RA(aQ2, bufR_, kh_, 6); RA(aQ3, bufR_, kh_, 7);                     \
    if (DOSTG) STG2(t2_, bufW_, 0, kh_);                                \
    BAR(); LGKM(4); PRIO(1);                                            \
    MMROW(0, aP0) MMROW(1, aP1) MMROW(2, aP2) MMROW(3, aP3)             \
    PRIO(0); BAR();                                                     \
    if (DOSTG) STG2(t2_, bufW_, 1, kh_);                                \
    BAR(); LGKM(0); PRIO(1);                                            \
    MMROW(4, aQ0) MMROW(5, aQ1) MMROW(6, aQ2) MMROW(7, aQ3)             \
    PRIO(0); VMTAIL1; BAR();                                            \
  } while (0)

#define TILE_STD(bufR_, bufW_, t2_) do {                                \
    HALF(bufR_, 0, t2_, bufW_, 1, VMC(4));                              \
    HALF(bufR_, 1, t2_, bufW_, 1, VMC(4));                              \
  } while (0)

  // prologue: tile 0 all chunks, order {A-kh0,B-kh0} then {A-kh1,B-kh1};
  // vmcnt(4) retires kh0 (leaves kh1 = steady-state "t-1 P2,P3"); publish.
  STG2(0, 0, 0, 0); STG2(0, 0, 1, 0);
  STG2(0, 0, 0, 1); STG2(0, 0, 1, 1);
  VMC(4);
  BAR();

  for (int u = 0; u < 15; ++u) {                   // tiles 0..29
    TILE_STD(0, 1, 2 * u + 1);
    TILE_STD(1, 0, 2 * u + 2);
  }
  TILE_STD(0, 1, 31);                              // tile 30 stages tile 31
  HALF(1, 0, 0, 0, 0, VMC(0));                     // tile 31: P1 drains all
  HALF(1, 1, 0, 0, 0, );                           // tile 31 kh1
#undef TILE_STD
#undef HALF

  VMC(0);
  BAR();                                           // LDS reuse boundary

  // ---- fused ON-LSTM epilogue: 4 row-passes, epi = f32[64][256] (64 KB) ----
  // LITERAL pass index (rule #20): all acc[] subscripts compile-time.
  float* epi = (float*)smem;
#define EPIPASS(p) do {                                                \
    if (wm == ((p) >> 1)) {                                            \
      _Pragma("unroll")                                                \
      for (int iq = 0; iq < 4; ++iq)                                   \
        _Pragma("unroll")                                              \
        for (int j = 0; j < 4; ++j)                                    \
          _Pragma("unroll")                                            \
          for (int r = 0; r < 4; ++r) {                                \
            float v = acc[((p) & 1) * 4 + iq][j][r];                   \
            v = ((c16 & 3) == 3) ? ftanhf(v) : fsig(v);                \
            epi[(iq * 16 + r16 * 4 + r) * 256 + wn * 64 + j * 16 + c16] = v; \
          }                                                            \
    }                                                                  \
    __syncthreads();                                                   \
    _Pragma("unroll")                                                  \
    for (int e = 0; e < 8; ++e) {                                      \
      int idx = (e << 9) + tid;                                        \
      int m = idx >> 6, jl = idx & 63;                                 \
      v4f v = *(const v4f*)(epi + m * 256 + (jl << 2));                \
      int rowg = rm * 256 + (p) * 64 + m;                              \
      int jg = cm * 64 + jl;                                           \
      float cp = cprev[rowg * 1024 + jg];                              \
      int lv = jg >> 4;                                                \
      float vih = ihp[(rowg << 6) + lv], vfh = fhp[(rowg << 6) + lv];  \
      float iv = v.x, fv = v.y, ov = v.z, gv = v.w;                    \
      float wq = vih * vfh;                                            \
      float c = wq * (fv * cp + iv * gv) + (vfh - wq) * cp + (vih - wq) * gv; \
      float h = ov * ftanhf(c);                                        \
      out[rowg * 1024 + jg] = h;                                       \
      out[8388608 + rowg * 1024 + jg] = c;                             \
    }                                                                  \
    __syncthreads();                                                   \
  } while (0)
  EPIPASS(0); EPIPASS(1); EPIPASS(2); EPIPASS(3);
#undef EPIPASS
}

// -------------------------------------------------------------- launcher ---
extern "C" void kernel_launch(void* const* d_in, const int* in_sizes, int n_in,
                              void* d_out, int out_size, void* d_ws, size_t ws_size,
                              hipStream_t stream) {
  (void)in_sizes; (void)n_in; (void)out_size; (void)ws_size;
  const float* inp   = (const float*)d_in[0];
  const float* hprev = (const float*)d_in[1];
  const float* cprev = (const float*)d_in[2];
  const float* wl    = (const float*)d_in[3];
  const float* wlev  = (const float*)d_in[4];
  float* out = (float*)d_out;
  char* ws = (char*)d_ws;

  u16* Ahi  = (u16*)(ws);
  u16* Alo  = (u16*)(ws + 33554432);
  u16* Whi  = (u16*)(ws + 67108864);
  u16* Wlo  = (u16*)(ws + 84410368);
  float* part = (float*)(ws + 84934656);
  float* ih   = (float*)(ws + 118489088);
  float* fh   = (float*)(ws + 120586240);

  k_convert<<<dim3(2048), dim3(256), 0, stream>>>(inp, hprev, wl, wlev, Ahi, Alo, Whi, Wlo);
  k_gemm_level<<<dim3(64, 8), dim3(256), 0, stream>>>(Ahi, Alo, Whi, Wlo, part);
  k_softmax<<<dim3(2048), dim3(256), 0, stream>>>(part, ih, fh);
  k_gemm_main<<<dim3(512), dim3(512), 0, stream>>>(Ahi, Whi, cprev, ih, fh, out);
}